// Round 5
// baseline (931.728 us; speedup 1.0000x reference)
//
#include <hip/hip_runtime.h>
#include <hip/hip_bf16.h>

// All inputs/outputs are float32 (per the reference file's setup_inputs).

// 16-lane butterfly sum via DPP (VALU, no DS-pipe traffic). All 16 lanes of
// each row-quarter end up holding the sum.
static __device__ __forceinline__ float dpp_sum16(float x)
{
    x += __int_as_float(__builtin_amdgcn_update_dpp(
        0, __float_as_int(x), 0xB1, 0xF, 0xF, true));   // quad_perm [1,0,3,2]  = xor1
    x += __int_as_float(__builtin_amdgcn_update_dpp(
        0, __float_as_int(x), 0x4E, 0xF, 0xF, true));   // quad_perm [2,3,0,1]  = xor2
    x += __int_as_float(__builtin_amdgcn_update_dpp(
        0, __float_as_int(x), 0x141, 0xF, 0xF, true));  // row_half_mirror      = xor4-equiv
    x += __int_as_float(__builtin_amdgcn_update_dpp(
        0, __float_as_int(x), 0x140, 0xF, 0xF, true));  // row_mirror           = xor8-equiv
    return x;
}

// ---------------------------------------------------------------------------
// 3x3 SAME conv, 64->64 ch, NCHW. Block = one (b,h) row, 256 threads.
// lane = w pixel (LDS reads lane-parallel, conflict-free); each wave owns 16
// output channels (co = wave*16+i) with readfirstlane-scalarized weight loads
// (s_load). LDS: 3 rows x 64ci x 64w = 48KB, staged as float4.
// ---------------------------------------------------------------------------
__global__ __launch_bounds__(256) void conv3x3_k(const float* __restrict__ in,
    const float* __restrict__ w, const float* __restrict__ bias,
    const float* __restrict__ addsrc, float* __restrict__ out)
{
    const int bh = blockIdx.x;
    const int b = bh >> 6, h = bh & 63;
    const int t = threadIdx.x;
    __shared__ float lin[3 * 4096];  // [r][ci][w]
    for (int e4 = t; e4 < 3072; e4 += 256) {
        const int flat = e4 * 4;
        const int r = flat >> 12, ci = (flat >> 6) & 63, w4 = flat & 63;
        const int hh = h - 1 + r;
        float4 v = make_float4(0.f, 0.f, 0.f, 0.f);
        if (hh >= 0 && hh < 64)
            v = *(const float4*)&in[((b * 64 + ci) * 64 + hh) * 64 + w4];
        *(float4*)&lin[flat] = v;
    }
    __syncthreads();
    const int wv = __builtin_amdgcn_readfirstlane(t >> 6);  // wave id 0..3 (SGPR)
    const int lane = t & 63;                                 // = w pixel
    const int co0 = wv * 16;
    float acc[16];
#pragma unroll
    for (int i = 0; i < 16; ++i) acc[i] = bias[co0 + i];
    for (int ci = 0; ci < 64; ++ci) {
        float rv[9];
#pragma unroll
        for (int r = 0; r < 3; ++r) {
            const float* row = &lin[r * 4096 + ci * 64];
            const float vc = row[lane];
            const float vm = (lane > 0) ? row[lane - 1] : 0.f;
            const float vn = (lane < 63) ? row[lane + 1] : 0.f;
            rv[r * 3 + 0] = vm; rv[r * 3 + 1] = vc; rv[r * 3 + 2] = vn;
        }
#pragma unroll
        for (int i = 0; i < 16; ++i) {
            const float* wp = w + ((co0 + i) * 64 + ci) * 9;  // uniform -> s_load
#pragma unroll
            for (int q = 0; q < 9; ++q) acc[i] = fmaf(rv[q], wp[q], acc[i]);
        }
    }
#pragma unroll
    for (int i = 0; i < 16; ++i) {
        const size_t o = ((size_t)(b * 64 + co0 + i) * 64 + h) * 64 + lane;
        float v = acc[i];
        if (addsrc) v += addsrc[o];
        out[o] = v;
    }
}

// ---------------------------------------------------------------------------
// InstanceNorm over HxW per (b,c) + LeakyReLU(0.2). Block per (b,c).
// ---------------------------------------------------------------------------
__global__ __launch_bounds__(256) void inorm_lrelu_k(const float* __restrict__ in,
                                                     float* __restrict__ out)
{
    const int bc = blockIdx.x;
    const float* row = in + (size_t)bc * 4096;
    float s1 = 0.f, s2 = 0.f;
    for (int i = threadIdx.x; i < 4096; i += 256) {
        const float v = row[i];
        s1 += v; s2 = fmaf(v, v, s2);
    }
#pragma unroll
    for (int mk = 1; mk < 64; mk <<= 1) {
        s1 += __shfl_xor(s1, mk, 64);
        s2 += __shfl_xor(s2, mk, 64);
    }
    __shared__ float a1[4], a2[4];
    const int wid = threadIdx.x >> 6;
    if ((threadIdx.x & 63) == 0) { a1[wid] = s1; a2[wid] = s2; }
    __syncthreads();
    const float S1 = a1[0] + a1[1] + a1[2] + a1[3];
    const float S2 = a2[0] + a2[1] + a2[2] + a2[3];
    const float mu = S1 * (1.f / 4096.f);
    const float var = S2 * (1.f / 4096.f) - mu * mu;
    const float rstd = rsqrtf(var + 1e-5f);
    float* orow = out + (size_t)bc * 4096;
    for (int i = threadIdx.x; i < 4096; i += 256) {
        float v = (row[i] - mu) * rstd;
        v = (v >= 0.f) ? v : 0.2f * v;
        orow[i] = v;
    }
}

// ---------------------------------------------------------------------------
// LayerNorm over 64 ch (NHWC view of x1) + in_proj (256x64). No LDS: thread
// = (co-group t>>5, position j=t&31); x row held in registers (global loads
// are coalesced, L2-hot); LN stats computed privately; register GEMM with
// float4 weight loads. Outputs xin (b,128,L) and z (b,l,128).
// ---------------------------------------------------------------------------
__global__ __launch_bounds__(256) void ln_inproj_k(const float* __restrict__ x1,
    const float* __restrict__ g, const float* __restrict__ be,
    const float* __restrict__ w, float* __restrict__ xin_raw, float* __restrict__ z)
{
    const int bx = blockIdx.x;
    const int b = bx >> 7, l0 = (bx & 127) * 32;
    const int t = threadIdx.x;
    const int j = t & 31, co0 = (t >> 5) * 32;
    float xr[64];
    float s1 = 0.f, s2 = 0.f;
#pragma unroll
    for (int c = 0; c < 64; ++c) {
        const float v = x1[(b * 64 + c) * 4096 + l0 + j];
        xr[c] = v; s1 += v; s2 = fmaf(v, v, s2);
    }
    const float mu = s1 * (1.f / 64.f);
    const float var = s2 * (1.f / 64.f) - mu * mu;
    const float rstd = rsqrtf(var + 1e-5f);
#pragma unroll
    for (int c = 0; c < 64; ++c)
        xr[c] = (xr[c] - mu) * rstd * g[c] + be[c];
    for (int i = 0; i < 32; ++i) {
        const int e = co0 + i;
        const float4* wp = (const float4*)(w + e * 64);
        float a = 0.f;
#pragma unroll
        for (int c4 = 0; c4 < 16; ++c4) {
            const float4 wv = wp[c4];
            a = fmaf(xr[c4 * 4 + 0], wv.x, a);
            a = fmaf(xr[c4 * 4 + 1], wv.y, a);
            a = fmaf(xr[c4 * 4 + 2], wv.z, a);
            a = fmaf(xr[c4 * 4 + 3], wv.w, a);
        }
        if (e < 128) xin_raw[(b * 128 + e) * 4096 + l0 + j] = a;
        else z[((size_t)(b * 4096 + l0 + j)) * 128 + (e - 128)] = a;
    }
}

// ---------------------------------------------------------------------------
// Depthwise 3x3 SAME conv + bias + SiLU on (b,128,64,64).
// ---------------------------------------------------------------------------
__global__ __launch_bounds__(256) void dwconv_silu_k(const float* __restrict__ in,
    const float* __restrict__ w, const float* __restrict__ bias, float* __restrict__ out)
{
    const int idx = blockIdx.x * 256 + threadIdx.x;  // (b*128+d)*4096 + l
    const int l = idx & 4095, bd = idx >> 12, d = bd & 127;
    const int hh = l >> 6, ww = l & 63;
    const float* base = in + (size_t)bd * 4096;
    float acc = bias[d];
    const float* wp = w + d * 9;
#pragma unroll
    for (int dy = 0; dy < 3; ++dy) {
        const int y = hh + dy - 1;
        if (y < 0 || y > 63) continue;
#pragma unroll
        for (int dx = 0; dx < 3; ++dx) {
            const int xx = ww + dx - 1;
            if (xx < 0 || xx > 63) continue;
            acc = fmaf(base[y * 64 + xx], wp[dy * 3 + dx], acc);
        }
    }
    out[idx] = acc / (1.f + __expf(-acc));  // silu
}

// ---------------------------------------------------------------------------
// 64x64 spatial transpose per (b,d): xin_T[wi*64+hi] = xin_s[hi*64+wi].
// ---------------------------------------------------------------------------
__global__ __launch_bounds__(256) void transpose_k(const float* __restrict__ in,
                                                   float* __restrict__ out)
{
    const int bd = blockIdx.x;
    __shared__ float tl[64 * 65];
    const float* src = in + (size_t)bd * 4096;
    for (int e = threadIdx.x; e < 4096; e += 256) {
        const int r = e >> 6, c = e & 63;
        tl[r * 65 + c] = src[e];
    }
    __syncthreads();
    float* dst = out + (size_t)bd * 4096;
    for (int e = threadIdx.x; e < 4096; e += 256) {
        const int wi = e >> 6, hi = e & 63;
        dst[e] = tl[hi * 65 + wi];
    }
}

// ---------------------------------------------------------------------------
// x_dbl[b,k,c,m] = sum_d xs[b,k,d,m] * x_proj_w[k,c,d]  (c=36, scan order m)
// ---------------------------------------------------------------------------
__global__ __launch_bounds__(256) void xdbl_k(const float* __restrict__ xin_s,
    const float* __restrict__ xin_T, const float* __restrict__ xpw,
    float* __restrict__ xdbl)
{
    const int bx = blockIdx.x;
    const int bk = bx >> 7, m0 = (bx & 127) * 32;
    const int b = bk >> 2, k = bk & 3;
    __shared__ float tl[128 * 33];
    const float* src = (k & 1) ? xin_T : xin_s;
    const bool rev = (k >= 2);
    for (int e = threadIdx.x; e < 4096; e += 256) {
        const int d = e >> 5, j = e & 31;
        const int m = m0 + j;
        const int um = rev ? (4095 - m) : m;
        tl[d * 33 + j] = src[(b * 128 + d) * 4096 + um];
    }
    __syncthreads();
    const int j = threadIdx.x & 31, c0 = threadIdx.x >> 5;
    float acc[5] = {0.f, 0.f, 0.f, 0.f, 0.f};
    for (int d = 0; d < 128; ++d) {
        const float v = tl[d * 33 + j];
#pragma unroll
        for (int q = 0; q < 5; ++q) {
            const int c = c0 + q * 8;
            if (c < 36) acc[q] = fmaf(v, xpw[(k * 36 + c) * 128 + d], acc[q]);
        }
    }
#pragma unroll
    for (int q = 0; q < 5; ++q) {
        const int c = c0 + q * 8;
        if (c < 36) xdbl[((size_t)bk * 36 + c) * 4096 + m0 + j] = acc[q];
    }
}

// ---------------------------------------------------------------------------
// Segmented selective scan, phase 1: per 128-step segment compute zero-start
// h_end and propagator prod(alpha) per (chain,n). LDS pad 132 (float4-aligned,
// 2-way conflict = free); compute loop reads ds_read_b128.
// Summary layout: [seg][ (bk*128+d)*16+n ] for coalesced store/combine/load.
// ---------------------------------------------------------------------------
__global__ __launch_bounds__(256) void scan_p1_k(const float* __restrict__ xdbl,
    const float* __restrict__ xin_s, const float* __restrict__ xin_T,
    const float* __restrict__ A_logs, const float* __restrict__ dtw,
    const float* __restrict__ dtb, float* __restrict__ hseg,
    float* __restrict__ pseg)
{
    const int bx = blockIdx.x;
    const int seg = bx & 31, d8 = (bx >> 5) & 7, bk = bx >> 8;
    const int b = bk >> 2, k = bk & 3;
    const int t = threadIdx.x;
    const int chain = t >> 4, n = t & 15;
    const int d = d8 * 16 + chain;
    const float A = -__expf(A_logs[(k * 128 + d) * 16 + n]);
    __shared__ float sB[16 * 132], sdt[16 * 132], su[16 * 132];
    const float* srcu = (k & 1) ? xin_T : xin_s;
    const bool rev = (k >= 2);
    const int jj = t & 127, half = t >> 7;
    const int m0 = seg * 128;
    {
        const float dts0 = xdbl[((size_t)bk * 36 + 0) * 4096 + m0 + jj];
        const float dts1 = xdbl[((size_t)bk * 36 + 1) * 4096 + m0 + jj];
        const float dts2 = xdbl[((size_t)bk * 36 + 2) * 4096 + m0 + jj];
        const float dts3 = xdbl[((size_t)bk * 36 + 3) * 4096 + m0 + jj];
        const int m = m0 + jj;
        const int um = rev ? (4095 - m) : m;
#pragma unroll
        for (int i = 0; i < 8; ++i) {
            const int nn = half + 2 * i;
            sB[nn * 132 + jj] = xdbl[((size_t)bk * 36 + 4 + nn) * 4096 + m0 + jj];
            const int dd = d8 * 16 + nn;
            const float* wp = dtw + (k * 128 + dd) * 4;
            float s = dtb[k * 128 + dd];
            s = fmaf(dts0, wp[0], s);
            s = fmaf(dts1, wp[1], s);
            s = fmaf(dts2, wp[2], s);
            s = fmaf(dts3, wp[3], s);
            sdt[nn * 132 + jj] = (s > 20.f) ? s : log1pf(__expf(s));
            su[nn * 132 + jj] = srcu[(b * 128 + dd) * 4096 + um];
        }
    }
    __syncthreads();
    const float4* B4  = (const float4*)(sB + n * 132);
    const float4* dt4 = (const float4*)(sdt + chain * 132);
    const float4* u4  = (const float4*)(su + chain * 132);
    float h = 0.f, pr = 1.f;
#pragma unroll 4
    for (int q = 0; q < 32; ++q) {
        const float4 dt = dt4[q], uu = u4[q], BB = B4[q];
        float a;
        a = __expf(dt.x * A); h = fmaf(h, a, dt.x * uu.x * BB.x); pr *= a;
        a = __expf(dt.y * A); h = fmaf(h, a, dt.y * uu.y * BB.y); pr *= a;
        a = __expf(dt.z * A); h = fmaf(h, a, dt.z * uu.z * BB.z); pr *= a;
        a = __expf(dt.w * A); h = fmaf(h, a, dt.w * uu.w * BB.w); pr *= a;
    }
    const size_t idx = (size_t)seg * 32768 + (size_t)(bk * 128 + d) * 16 + n;
    hseg[idx] = h;
    pseg[idx] = pr;
}

// ---------------------------------------------------------------------------
// Combine segment summaries sequentially (32 per chain-state), coalesced:
// element i of segment s lives at s*32768+i. pseg is overwritten with h_start.
// ---------------------------------------------------------------------------
__global__ __launch_bounds__(256) void scan_combine_k(const float* __restrict__ hseg,
                                                      float* __restrict__ pseg)
{
    const int i = blockIdx.x * 256 + threadIdx.x;  // 0..32767
    float h = 0.f;
#pragma unroll 4
    for (int s = 0; s < 32; ++s) {
        const size_t idx = (size_t)s * 32768 + i;
        const float p = pseg[idx];
        const float he = hseg[idx];
        pseg[idx] = h;             // h_start for segment s
        h = fmaf(h, p, he);        // exact recurrence on summaries
    }
}

// ---------------------------------------------------------------------------
// Segmented scan, phase 2: recurrence seeded with h_start; y via DPP 16-lane
// butterfly (VALU) + one atomicAdd per chain-step into y_total[b,l_orig,d].
// ---------------------------------------------------------------------------
__global__ __launch_bounds__(256) void scan_p2_k(const float* __restrict__ xdbl,
    const float* __restrict__ xin_s, const float* __restrict__ xin_T,
    const float* __restrict__ A_logs, const float* __restrict__ dtw,
    const float* __restrict__ dtb, const float* __restrict__ hstart,
    float* __restrict__ y_total)
{
    const int bx = blockIdx.x;
    const int seg = bx & 31, d8 = (bx >> 5) & 7, bk = bx >> 8;
    const int b = bk >> 2, k = bk & 3;
    const int t = threadIdx.x;
    const int chain = t >> 4, n = t & 15;
    const int d = d8 * 16 + chain;
    const float A = -__expf(A_logs[(k * 128 + d) * 16 + n]);
    __shared__ float sB[16 * 132], sC[16 * 132], sdt[16 * 132], su[16 * 132];
    const float* srcu = (k & 1) ? xin_T : xin_s;
    const bool rev = (k >= 2);
    const int jj = t & 127, half = t >> 7;
    const int m0 = seg * 128;
    {
        const float dts0 = xdbl[((size_t)bk * 36 + 0) * 4096 + m0 + jj];
        const float dts1 = xdbl[((size_t)bk * 36 + 1) * 4096 + m0 + jj];
        const float dts2 = xdbl[((size_t)bk * 36 + 2) * 4096 + m0 + jj];
        const float dts3 = xdbl[((size_t)bk * 36 + 3) * 4096 + m0 + jj];
        const int m = m0 + jj;
        const int um = rev ? (4095 - m) : m;
#pragma unroll
        for (int i = 0; i < 8; ++i) {
            const int nn = half + 2 * i;
            sB[nn * 132 + jj] = xdbl[((size_t)bk * 36 + 4 + nn) * 4096 + m0 + jj];
            sC[nn * 132 + jj] = xdbl[((size_t)bk * 36 + 20 + nn) * 4096 + m0 + jj];
            const int dd = d8 * 16 + nn;
            const float* wp = dtw + (k * 128 + dd) * 4;
            float s = dtb[k * 128 + dd];
            s = fmaf(dts0, wp[0], s);
            s = fmaf(dts1, wp[1], s);
            s = fmaf(dts2, wp[2], s);
            s = fmaf(dts3, wp[3], s);
            sdt[nn * 132 + jj] = (s > 20.f) ? s : log1pf(__expf(s));
            su[nn * 132 + jj] = srcu[(b * 128 + dd) * 4096 + um];
        }
    }
    __syncthreads();
    const float4* B4  = (const float4*)(sB + n * 132);
    const float4* C4  = (const float4*)(sC + n * 132);
    const float4* dt4 = (const float4*)(sdt + chain * 132);
    const float4* u4  = (const float4*)(su + chain * 132);
    float h = hstart[(size_t)seg * 32768 + (size_t)(bk * 128 + d) * 16 + n];
#pragma unroll 4
    for (int q = 0; q < 32; ++q) {
        const float4 dt = dt4[q], uu = u4[q], BB = B4[q], CC = C4[q];
        float a, p;
#define SCAN_STEP(E, IDX)                                                     \
        a = __expf(dt.E * A);                                                 \
        h = fmaf(h, a, dt.E * uu.E * BB.E);                                   \
        p = dpp_sum16(h * CC.E);                                              \
        if (n == 0) {                                                         \
            const int mm2 = m0 + q * 4 + IDX;                                 \
            int l;                                                            \
            if (k == 0) l = mm2;                                              \
            else if (k == 1) l = ((mm2 & 63) << 6) | (mm2 >> 6);              \
            else if (k == 2) l = 4095 - mm2;                                  \
            else { const int mf = 4095 - mm2; l = ((mf & 63) << 6) | (mf >> 6); } \
            atomicAdd(&y_total[((size_t)b * 4096 + l) * 128 + d], p);         \
        }
        SCAN_STEP(x, 0)
        SCAN_STEP(y, 1)
        SCAN_STEP(z, 2)
        SCAN_STEP(w, 3)
#undef SCAN_STEP
    }
}

// ---------------------------------------------------------------------------
// Finalize: y += (sum_k Ds)*u; LN over 128; * silu(z); out_proj (64x128 GEMV);
// + skip_scale*x1  -> res (NCHW). Block per (b,l), 128 threads.
// ---------------------------------------------------------------------------
__global__ __launch_bounds__(128) void finalize_k(const float* __restrict__ y_total,
    const float* __restrict__ xin_s, const float* __restrict__ z,
    const float* __restrict__ x1, const float* __restrict__ Dsp,
    const float* __restrict__ ong, const float* __restrict__ onb,
    const float* __restrict__ opw, const float* __restrict__ skipp,
    float* __restrict__ res)
{
    const int bi = blockIdx.x;
    const int b = bi >> 12, l = bi & 4095;
    const int d = threadIdx.x;
    const float Dsum = Dsp[d] + Dsp[128 + d] + Dsp[256 + d] + Dsp[384 + d];
    const float u = xin_s[(b * 128 + d) * 4096 + l];
    const float v = y_total[((size_t)b * 4096 + l) * 128 + d] + Dsum * u;
    float s1 = v, s2 = v * v;
#pragma unroll
    for (int mk = 1; mk < 64; mk <<= 1) {
        s1 += __shfl_xor(s1, mk, 64);
        s2 += __shfl_xor(s2, mk, 64);
    }
    __shared__ float r1[2], r2[2];
    __shared__ float yl[128];
    if ((d & 63) == 0) { r1[d >> 6] = s1; r2[d >> 6] = s2; }
    __syncthreads();
    const float S1 = r1[0] + r1[1], S2 = r2[0] + r2[1];
    const float mu = S1 * (1.f / 128.f);
    const float var = S2 * (1.f / 128.f) - mu * mu;
    const float rstd = rsqrtf(var + 1e-5f);
    const float yln = (v - mu) * rstd * ong[d] + onb[d];
    const float zz = z[((size_t)b * 4096 + l) * 128 + d];
    yl[d] = yln * (zz / (1.f + __expf(-zz)));
    __syncthreads();
    if (d < 64) {
        float acc = 0.f;
        const float* wp = opw + d * 128;
        for (int dd = 0; dd < 128; ++dd) acc = fmaf(yl[dd], wp[dd], acc);
        res[(b * 64 + d) * 4096 + l] = acc + skipp[0] * x1[(b * 64 + d) * 4096 + l];
    }
}

// ---------------------------------------------------------------------------
// Workspace layout (floats), total 13,893,632 floats = 53.0 MB:
//   x1     @ 0          (1,048,576)   live: cf-conv .. cb-conv
//   xin_s  @ 1,048,576  (2,097,152)   live: dwconv .. finalize
//   zbuf   @ 3,145,728  (2,097,152)   live: ln_inproj .. finalize
//   xin_T  @ 5,242,880  (2,097,152)   live: transpose .. scan p2
//   xdbl   @ 7,340,032  (2,359,296)   live: xdbl_k .. scan p2
//   ytot   @ 9,699,328  (2,097,152)   live: scan p2 .. finalize
//   G      @ 11,796,480 (2,097,152)   scratch, reused:
//     conv chain (G0/G1), xin_raw (full G),
//     hseg=G0 / pseg->hstart=G1 during scan (each exactly 1,048,576),
//     res=G0 / tmp=G1 after finalize
// ---------------------------------------------------------------------------
extern "C" void kernel_launch(void* const* d_in, const int* in_sizes, int n_in,
                              void* d_out, int out_size, void* d_ws, size_t ws_size,
                              hipStream_t stream)
{
    const float* x          = (const float*)d_in[0];
    const float* conv1_w    = (const float*)d_in[1];
    const float* conv1_b    = (const float*)d_in[2];
    const float* conv2_w    = (const float*)d_in[3];
    const float* conv2_b    = (const float*)d_in[4];
    const float* cf_w       = (const float*)d_in[5];
    const float* cf_b       = (const float*)d_in[6];
    const float* ln_g       = (const float*)d_in[7];
    const float* ln_b       = (const float*)d_in[8];
    const float* in_proj_w  = (const float*)d_in[9];
    const float* dw_w       = (const float*)d_in[10];
    const float* dw_b       = (const float*)d_in[11];
    const float* x_proj_w   = (const float*)d_in[12];
    const float* dt_proj_w  = (const float*)d_in[13];
    const float* dt_proj_b  = (const float*)d_in[14];
    const float* A_logs     = (const float*)d_in[15];
    const float* Ds         = (const float*)d_in[16];
    const float* out_norm_g = (const float*)d_in[17];
    const float* out_norm_b = (const float*)d_in[18];
    const float* out_proj_w = (const float*)d_in[19];
    const float* skip_scale = (const float*)d_in[20];
    const float* cb_w       = (const float*)d_in[21];
    const float* cb_b       = (const float*)d_in[22];

    float* ws = (float*)d_ws;
    float* x1    = ws;                 // 1,048,576
    float* xin_s = ws + 1048576;       // 2,097,152
    float* zbuf  = ws + 3145728;       // 2,097,152
    float* xin_T = ws + 5242880;       // 2,097,152
    float* xdbl  = ws + 7340032;       // 2,359,296
    float* ytot  = ws + 9699328;       // 2,097,152
    float* G     = ws + 11796480;      // 2,097,152 scratch
    float* G0 = G;
    float* G1 = G + 1048576;

    hipMemsetAsync(ytot, 0, 2097152 * sizeof(float), stream);

    conv3x3_k<<<256, 256, 0, stream>>>(x, conv1_w, conv1_b, nullptr, G0);
    inorm_lrelu_k<<<256, 256, 0, stream>>>(G0, G1);
    conv3x3_k<<<256, 256, 0, stream>>>(G1, conv2_w, conv2_b, nullptr, G0);
    conv3x3_k<<<256, 256, 0, stream>>>(G0, cf_w, cf_b, nullptr, x1);
    ln_inproj_k<<<512, 256, 0, stream>>>(x1, ln_g, ln_b, in_proj_w, G /*xin_raw*/, zbuf);
    dwconv_silu_k<<<8192, 256, 0, stream>>>(G /*xin_raw*/, dw_w, dw_b, xin_s);
    transpose_k<<<512, 256, 0, stream>>>(xin_s, xin_T);
    xdbl_k<<<2048, 256, 0, stream>>>(xin_s, xin_T, x_proj_w, xdbl);
    // segmented scan: G is free again (xin_raw dead after dwconv)
    scan_p1_k<<<4096, 256, 0, stream>>>(xdbl, xin_s, xin_T, A_logs, dt_proj_w,
                                        dt_proj_b, G0 /*hseg*/, G1 /*pseg*/);
    scan_combine_k<<<128, 256, 0, stream>>>(G0 /*hseg*/, G1 /*pseg->hstart*/);
    scan_p2_k<<<4096, 256, 0, stream>>>(xdbl, xin_s, xin_T, A_logs, dt_proj_w,
                                        dt_proj_b, G1 /*hstart*/, ytot);
    finalize_k<<<16384, 128, 0, stream>>>(ytot, xin_s, zbuf, x1, Ds, out_norm_g,
                                          out_norm_b, out_proj_w, skip_scale, G0 /*res*/);
    conv3x3_k<<<256, 256, 0, stream>>>(G0 /*res*/, cb_w, cb_b, x1, G1 /*tmp*/);
    inorm_lrelu_k<<<256, 256, 0, stream>>>(G1 /*tmp*/, (float*)d_out);
}

// Round 6
// 782.792 us; speedup vs baseline: 1.1903x; 1.1903x over previous
//
#include <hip/hip_runtime.h>
#include <hip/hip_bf16.h>

// All inputs/outputs are float32 (per the reference file's setup_inputs).

// 16-lane butterfly sum via DPP (VALU, no DS-pipe traffic). All 16 lanes of
// each row end up holding the sum of their 16-lane group.
static __device__ __forceinline__ float dpp_sum16(float x)
{
    x += __int_as_float(__builtin_amdgcn_update_dpp(
        0, __float_as_int(x), 0xB1, 0xF, 0xF, true));   // quad_perm [1,0,3,2]
    x += __int_as_float(__builtin_amdgcn_update_dpp(
        0, __float_as_int(x), 0x4E, 0xF, 0xF, true));   // quad_perm [2,3,0,1]
    x += __int_as_float(__builtin_amdgcn_update_dpp(
        0, __float_as_int(x), 0x141, 0xF, 0xF, true));  // row_half_mirror
    x += __int_as_float(__builtin_amdgcn_update_dpp(
        0, __float_as_int(x), 0x140, 0xF, 0xF, true));  // row_mirror
    return x;
}

// ---------------------------------------------------------------------------
// 3x3 SAME conv, 64->64 ch, NCHW. Block = one (b,h) row, 256 threads.
// lane = w pixel (LDS reads lane-parallel, conflict-free); wave owns 16 co.
// Weights read as per-lane float4 vector loads (uniform address -> single
// coalesced L1-hot transaction; VMEM pipe hides latency, no scalar path).
// ci chunked by 4 so each (co, ci..ci+3) weight block is 36 floats, 16B
// aligned -> 9x float4. 1 block/CU: VGPR pressure is free, full unroll.
// ---------------------------------------------------------------------------
__global__ __launch_bounds__(256) void conv3x3_k(const float* __restrict__ in,
    const float* __restrict__ w, const float* __restrict__ bias,
    const float* __restrict__ addsrc, float* __restrict__ out)
{
    const int bh = blockIdx.x;
    const int b = bh >> 6, h = bh & 63;
    const int t = threadIdx.x;
    __shared__ float lin[3 * 4096];  // [r][ci][w]
    for (int e4 = t; e4 < 3072; e4 += 256) {
        const int flat = e4 * 4;
        const int r = flat >> 12, ci = (flat >> 6) & 63, w4 = flat & 63;
        const int hh = h - 1 + r;
        float4 v = make_float4(0.f, 0.f, 0.f, 0.f);
        if (hh >= 0 && hh < 64)
            v = *(const float4*)&in[((b * 64 + ci) * 64 + hh) * 64 + w4];
        *(float4*)&lin[flat] = v;
    }
    __syncthreads();
    const int wv = t >> 6;       // wave id 0..3
    const int lane = t & 63;     // = w pixel
    const int co0 = wv * 16;
    float acc[16];
#pragma unroll
    for (int i = 0; i < 16; ++i) acc[i] = bias[co0 + i];

    for (int ci4 = 0; ci4 < 64; ci4 += 4) {
        // input for 4 ci x 3 rows: vm,vc,vn each  -> 36 regs
        float rvv[36];
#pragma unroll
        for (int c = 0; c < 4; ++c) {
#pragma unroll
            for (int r = 0; r < 3; ++r) {
                const float* row = &lin[r * 4096 + (ci4 + c) * 64];
                const float vc = row[lane];
                const float vm = (lane > 0) ? row[lane - 1] : 0.f;
                const float vn = (lane < 63) ? row[lane + 1] : 0.f;
                rvv[c * 9 + r * 3 + 0] = vm;
                rvv[c * 9 + r * 3 + 1] = vc;
                rvv[c * 9 + r * 3 + 2] = vn;
            }
        }
#pragma unroll
        for (int i = 0; i < 16; ++i) {
            // 36 consecutive floats = w[co0+i][ci4..ci4+3][0..8], 16B aligned
            const float4* wq = (const float4*)(w + ((size_t)(co0 + i) * 64 + ci4) * 9);
            float wf[36];
#pragma unroll
            for (int m = 0; m < 9; ++m) *(float4*)&wf[m * 4] = wq[m];
#pragma unroll
            for (int q = 0; q < 36; ++q) acc[i] = fmaf(rvv[q], wf[q], acc[i]);
        }
    }
#pragma unroll
    for (int i = 0; i < 16; ++i) {
        const size_t o = ((size_t)(b * 64 + co0 + i) * 64 + h) * 64 + lane;
        float v = acc[i];
        if (addsrc) v += addsrc[o];
        out[o] = v;
    }
}

// ---------------------------------------------------------------------------
// InstanceNorm over HxW per (b,c) + LeakyReLU(0.2). Block per (b,c).
// ---------------------------------------------------------------------------
__global__ __launch_bounds__(256) void inorm_lrelu_k(const float* __restrict__ in,
                                                     float* __restrict__ out)
{
    const int bc = blockIdx.x;
    const float* row = in + (size_t)bc * 4096;
    float s1 = 0.f, s2 = 0.f;
    for (int i = threadIdx.x; i < 4096; i += 256) {
        const float v = row[i];
        s1 += v; s2 = fmaf(v, v, s2);
    }
#pragma unroll
    for (int mk = 1; mk < 64; mk <<= 1) {
        s1 += __shfl_xor(s1, mk, 64);
        s2 += __shfl_xor(s2, mk, 64);
    }
    __shared__ float a1[4], a2[4];
    const int wid = threadIdx.x >> 6;
    if ((threadIdx.x & 63) == 0) { a1[wid] = s1; a2[wid] = s2; }
    __syncthreads();
    const float S1 = a1[0] + a1[1] + a1[2] + a1[3];
    const float S2 = a2[0] + a2[1] + a2[2] + a2[3];
    const float mu = S1 * (1.f / 4096.f);
    const float var = S2 * (1.f / 4096.f) - mu * mu;
    const float rstd = rsqrtf(var + 1e-5f);
    float* orow = out + (size_t)bc * 4096;
    for (int i = threadIdx.x; i < 4096; i += 256) {
        float v = (row[i] - mu) * rstd;
        v = (v >= 0.f) ? v : 0.2f * v;
        orow[i] = v;
    }
}

// ---------------------------------------------------------------------------
// LayerNorm over 64 ch (NHWC view of x1) + in_proj (256x64). No LDS.
// ---------------------------------------------------------------------------
__global__ __launch_bounds__(256) void ln_inproj_k(const float* __restrict__ x1,
    const float* __restrict__ g, const float* __restrict__ be,
    const float* __restrict__ w, float* __restrict__ xin_raw, float* __restrict__ z)
{
    const int bx = blockIdx.x;
    const int b = bx >> 7, l0 = (bx & 127) * 32;
    const int t = threadIdx.x;
    const int j = t & 31, co0 = (t >> 5) * 32;
    float xr[64];
    float s1 = 0.f, s2 = 0.f;
#pragma unroll
    for (int c = 0; c < 64; ++c) {
        const float v = x1[(b * 64 + c) * 4096 + l0 + j];
        xr[c] = v; s1 += v; s2 = fmaf(v, v, s2);
    }
    const float mu = s1 * (1.f / 64.f);
    const float var = s2 * (1.f / 64.f) - mu * mu;
    const float rstd = rsqrtf(var + 1e-5f);
#pragma unroll
    for (int c = 0; c < 64; ++c)
        xr[c] = (xr[c] - mu) * rstd * g[c] + be[c];
    for (int i = 0; i < 32; ++i) {
        const int e = co0 + i;
        const float4* wp = (const float4*)(w + e * 64);
        float a = 0.f;
#pragma unroll
        for (int c4 = 0; c4 < 16; ++c4) {
            const float4 wv = wp[c4];
            a = fmaf(xr[c4 * 4 + 0], wv.x, a);
            a = fmaf(xr[c4 * 4 + 1], wv.y, a);
            a = fmaf(xr[c4 * 4 + 2], wv.z, a);
            a = fmaf(xr[c4 * 4 + 3], wv.w, a);
        }
        if (e < 128) xin_raw[(b * 128 + e) * 4096 + l0 + j] = a;
        else z[((size_t)(b * 4096 + l0 + j)) * 128 + (e - 128)] = a;
    }
}

// ---------------------------------------------------------------------------
// Depthwise 3x3 SAME conv + bias + SiLU on (b,128,64,64).
// ---------------------------------------------------------------------------
__global__ __launch_bounds__(256) void dwconv_silu_k(const float* __restrict__ in,
    const float* __restrict__ w, const float* __restrict__ bias, float* __restrict__ out)
{
    const int idx = blockIdx.x * 256 + threadIdx.x;  // (b*128+d)*4096 + l
    const int l = idx & 4095, bd = idx >> 12, d = bd & 127;
    const int hh = l >> 6, ww = l & 63;
    const float* base = in + (size_t)bd * 4096;
    float acc = bias[d];
    const float* wp = w + d * 9;
#pragma unroll
    for (int dy = 0; dy < 3; ++dy) {
        const int y = hh + dy - 1;
        if (y < 0 || y > 63) continue;
#pragma unroll
        for (int dx = 0; dx < 3; ++dx) {
            const int xx = ww + dx - 1;
            if (xx < 0 || xx > 63) continue;
            acc = fmaf(base[y * 64 + xx], wp[dy * 3 + dx], acc);
        }
    }
    out[idx] = acc / (1.f + __expf(-acc));  // silu
}

// ---------------------------------------------------------------------------
// 64x64 spatial transpose per (b,d).
// ---------------------------------------------------------------------------
__global__ __launch_bounds__(256) void transpose_k(const float* __restrict__ in,
                                                   float* __restrict__ out)
{
    const int bd = blockIdx.x;
    __shared__ float tl[64 * 65];
    const float* src = in + (size_t)bd * 4096;
    for (int e = threadIdx.x; e < 4096; e += 256) {
        const int r = e >> 6, c = e & 63;
        tl[r * 65 + c] = src[e];
    }
    __syncthreads();
    float* dst = out + (size_t)bd * 4096;
    for (int e = threadIdx.x; e < 4096; e += 256) {
        const int wi = e >> 6, hi = e & 63;
        dst[e] = tl[hi * 65 + wi];
    }
}

// ---------------------------------------------------------------------------
// x_dbl[b,k,c,m] = sum_d xs[b,k,d,m] * x_proj_w[k,c,d]  (c=36, scan order m)
// ---------------------------------------------------------------------------
__global__ __launch_bounds__(256) void xdbl_k(const float* __restrict__ xin_s,
    const float* __restrict__ xin_T, const float* __restrict__ xpw,
    float* __restrict__ xdbl)
{
    const int bx = blockIdx.x;
    const int bk = bx >> 7, m0 = (bx & 127) * 32;
    const int b = bk >> 2, k = bk & 3;
    __shared__ float tl[128 * 33];
    const float* src = (k & 1) ? xin_T : xin_s;
    const bool rev = (k >= 2);
    for (int e = threadIdx.x; e < 4096; e += 256) {
        const int d = e >> 5, j = e & 31;
        const int m = m0 + j;
        const int um = rev ? (4095 - m) : m;
        tl[d * 33 + j] = src[(b * 128 + d) * 4096 + um];
    }
    __syncthreads();
    const int j = threadIdx.x & 31, c0 = threadIdx.x >> 5;
    float acc[5] = {0.f, 0.f, 0.f, 0.f, 0.f};
    for (int d = 0; d < 128; ++d) {
        const float v = tl[d * 33 + j];
#pragma unroll
        for (int q = 0; q < 5; ++q) {
            const int c = c0 + q * 8;
            if (c < 36) acc[q] = fmaf(v, xpw[(k * 36 + c) * 128 + d], acc[q]);
        }
    }
#pragma unroll
    for (int q = 0; q < 5; ++q) {
        const int c = c0 + q * 8;
        if (c < 36) xdbl[((size_t)bk * 36 + c) * 4096 + m0 + j] = acc[q];
    }
}

// ---------------------------------------------------------------------------
// Segmented selective scan, phase 1 (unchanged from R5).
// ---------------------------------------------------------------------------
__global__ __launch_bounds__(256) void scan_p1_k(const float* __restrict__ xdbl,
    const float* __restrict__ xin_s, const float* __restrict__ xin_T,
    const float* __restrict__ A_logs, const float* __restrict__ dtw,
    const float* __restrict__ dtb, float* __restrict__ hseg,
    float* __restrict__ pseg)
{
    const int bx = blockIdx.x;
    const int seg = bx & 31, d8 = (bx >> 5) & 7, bk = bx >> 8;
    const int b = bk >> 2, k = bk & 3;
    const int t = threadIdx.x;
    const int chain = t >> 4, n = t & 15;
    const int d = d8 * 16 + chain;
    const float A = -__expf(A_logs[(k * 128 + d) * 16 + n]);
    __shared__ float sB[16 * 132], sdt[16 * 132], su[16 * 132];
    const float* srcu = (k & 1) ? xin_T : xin_s;
    const bool rev = (k >= 2);
    const int jj = t & 127, half = t >> 7;
    const int m0 = seg * 128;
    {
        const float dts0 = xdbl[((size_t)bk * 36 + 0) * 4096 + m0 + jj];
        const float dts1 = xdbl[((size_t)bk * 36 + 1) * 4096 + m0 + jj];
        const float dts2 = xdbl[((size_t)bk * 36 + 2) * 4096 + m0 + jj];
        const float dts3 = xdbl[((size_t)bk * 36 + 3) * 4096 + m0 + jj];
        const int m = m0 + jj;
        const int um = rev ? (4095 - m) : m;
#pragma unroll
        for (int i = 0; i < 8; ++i) {
            const int nn = half + 2 * i;
            sB[nn * 132 + jj] = xdbl[((size_t)bk * 36 + 4 + nn) * 4096 + m0 + jj];
            const int dd = d8 * 16 + nn;
            const float* wp = dtw + (k * 128 + dd) * 4;
            float s = dtb[k * 128 + dd];
            s = fmaf(dts0, wp[0], s);
            s = fmaf(dts1, wp[1], s);
            s = fmaf(dts2, wp[2], s);
            s = fmaf(dts3, wp[3], s);
            sdt[nn * 132 + jj] = (s > 20.f) ? s : log1pf(__expf(s));
            su[nn * 132 + jj] = srcu[(b * 128 + dd) * 4096 + um];
        }
    }
    __syncthreads();
    const float4* B4  = (const float4*)(sB + n * 132);
    const float4* dt4 = (const float4*)(sdt + chain * 132);
    const float4* u4  = (const float4*)(su + chain * 132);
    float h = 0.f, pr = 1.f;
#pragma unroll 4
    for (int q = 0; q < 32; ++q) {
        const float4 dt = dt4[q], uu = u4[q], BB = B4[q];
        float a;
        a = __expf(dt.x * A); h = fmaf(h, a, dt.x * uu.x * BB.x); pr *= a;
        a = __expf(dt.y * A); h = fmaf(h, a, dt.y * uu.y * BB.y); pr *= a;
        a = __expf(dt.z * A); h = fmaf(h, a, dt.z * uu.z * BB.z); pr *= a;
        a = __expf(dt.w * A); h = fmaf(h, a, dt.w * uu.w * BB.w); pr *= a;
    }
    const size_t idx = (size_t)seg * 32768 + (size_t)(bk * 128 + d) * 16 + n;
    hseg[idx] = h;
    pseg[idx] = pr;
}

// ---------------------------------------------------------------------------
// Combine segment summaries (coalesced). pseg is overwritten with h_start.
// ---------------------------------------------------------------------------
__global__ __launch_bounds__(256) void scan_combine_k(const float* __restrict__ hseg,
                                                      float* __restrict__ pseg)
{
    const int i = blockIdx.x * 256 + threadIdx.x;  // 0..32767
    float h = 0.f;
#pragma unroll 4
    for (int s = 0; s < 32; ++s) {
        const size_t idx = (size_t)s * 32768 + i;
        const float p = pseg[idx];
        const float he = hseg[idx];
        pseg[idx] = h;
        h = fmaf(h, p, he);
    }
}

// ---------------------------------------------------------------------------
// Segmented scan, phase 2: recurrence seeded with h_start; y via DPP butterfly
// into an LDS tile [128 steps x 16 d], then bulk coalesced store into
// ybuf[k][b][m][d] (no atomics — each block owns a unique (k,b,d16,seg) tile).
// ---------------------------------------------------------------------------
__global__ __launch_bounds__(256) void scan_p2_k(const float* __restrict__ xdbl,
    const float* __restrict__ xin_s, const float* __restrict__ xin_T,
    const float* __restrict__ A_logs, const float* __restrict__ dtw,
    const float* __restrict__ dtb, const float* __restrict__ hstart,
    float* __restrict__ ybuf)
{
    const int bx = blockIdx.x;
    const int seg = bx & 31, d8 = (bx >> 5) & 7, bk = bx >> 8;
    const int b = bk >> 2, k = bk & 3;
    const int t = threadIdx.x;
    const int chain = t >> 4, n = t & 15;
    const int d = d8 * 16 + chain;
    const float A = -__expf(A_logs[(k * 128 + d) * 16 + n]);
    __shared__ float sB[16 * 132], sC[16 * 132], sdt[16 * 132], su[16 * 132];
    __shared__ float sy[128 * 16];  // [j][dd]
    const float* srcu = (k & 1) ? xin_T : xin_s;
    const bool rev = (k >= 2);
    const int jj = t & 127, half = t >> 7;
    const int m0 = seg * 128;
    {
        const float dts0 = xdbl[((size_t)bk * 36 + 0) * 4096 + m0 + jj];
        const float dts1 = xdbl[((size_t)bk * 36 + 1) * 4096 + m0 + jj];
        const float dts2 = xdbl[((size_t)bk * 36 + 2) * 4096 + m0 + jj];
        const float dts3 = xdbl[((size_t)bk * 36 + 3) * 4096 + m0 + jj];
        const int m = m0 + jj;
        const int um = rev ? (4095 - m) : m;
#pragma unroll
        for (int i = 0; i < 8; ++i) {
            const int nn = half + 2 * i;
            sB[nn * 132 + jj] = xdbl[((size_t)bk * 36 + 4 + nn) * 4096 + m0 + jj];
            sC[nn * 132 + jj] = xdbl[((size_t)bk * 36 + 20 + nn) * 4096 + m0 + jj];
            const int dd = d8 * 16 + nn;
            const float* wp = dtw + (k * 128 + dd) * 4;
            float s = dtb[k * 128 + dd];
            s = fmaf(dts0, wp[0], s);
            s = fmaf(dts1, wp[1], s);
            s = fmaf(dts2, wp[2], s);
            s = fmaf(dts3, wp[3], s);
            sdt[nn * 132 + jj] = (s > 20.f) ? s : log1pf(__expf(s));
            su[nn * 132 + jj] = srcu[(b * 128 + dd) * 4096 + um];
        }
    }
    __syncthreads();
    const float4* B4  = (const float4*)(sB + n * 132);
    const float4* C4  = (const float4*)(sC + n * 132);
    const float4* dt4 = (const float4*)(sdt + chain * 132);
    const float4* u4  = (const float4*)(su + chain * 132);
    float h = hstart[(size_t)seg * 32768 + (size_t)(bk * 128 + d) * 16 + n];
#pragma unroll 4
    for (int q = 0; q < 32; ++q) {
        const float4 dt = dt4[q], uu = u4[q], BB = B4[q], CC = C4[q];
        float a, p;
#define SCAN_STEP(E, IDX)                                                     \
        a = __expf(dt.E * A);                                                 \
        h = fmaf(h, a, dt.E * uu.E * BB.E);                                   \
        p = dpp_sum16(h * CC.E);                                              \
        if (n == 0) sy[(q * 4 + IDX) * 16 + chain] = p;
        SCAN_STEP(x, 0)
        SCAN_STEP(y, 1)
        SCAN_STEP(z, 2)
        SCAN_STEP(w, 3)
#undef SCAN_STEP
    }
    __syncthreads();
    // bulk store: ybuf[k][b][m0+j][d8*16+dd], 2048 elements, coalesced
    float* yk = ybuf + ((size_t)(k * 4 + b) * 4096) * 128;
#pragma unroll
    for (int p2 = 0; p2 < 8; ++p2) {
        const int e = p2 * 256 + t;
        const int j = e >> 4, dd = e & 15;
        yk[(size_t)(m0 + j) * 128 + d8 * 16 + dd] = sy[j * 16 + dd];
    }
}

// ---------------------------------------------------------------------------
// Finalize: y = sum of 4 direction buffers (inverse index maps) + Dsum*u;
// LN over 128; * silu(z); out_proj (64x128 GEMV); + skip*x1 -> res (NCHW).
// Block per (b,l), 128 threads.
// ---------------------------------------------------------------------------
__global__ __launch_bounds__(128) void finalize_k(const float* __restrict__ ybuf,
    const float* __restrict__ xin_s, const float* __restrict__ z,
    const float* __restrict__ x1, const float* __restrict__ Dsp,
    const float* __restrict__ ong, const float* __restrict__ onb,
    const float* __restrict__ opw, const float* __restrict__ skipp,
    float* __restrict__ res)
{
    const int bi = blockIdx.x;
    const int b = bi >> 12, l = bi & 4095;
    const int d = threadIdx.x;
    const int lT = ((l & 63) << 6) | (l >> 6);
    const float Dsum = Dsp[d] + Dsp[128 + d] + Dsp[256 + d] + Dsp[384 + d];
    const float u = xin_s[(b * 128 + d) * 4096 + l];
    const float y0 = ybuf[((size_t)(0 * 4 + b) * 4096 + l) * 128 + d];
    const float y1 = ybuf[((size_t)(1 * 4 + b) * 4096 + lT) * 128 + d];
    const float y2 = ybuf[((size_t)(2 * 4 + b) * 4096 + (4095 - l)) * 128 + d];
    const float y3 = ybuf[((size_t)(3 * 4 + b) * 4096 + (4095 - lT)) * 128 + d];
    const float v = y0 + y1 + y2 + y3 + Dsum * u;
    float s1 = v, s2 = v * v;
#pragma unroll
    for (int mk = 1; mk < 64; mk <<= 1) {
        s1 += __shfl_xor(s1, mk, 64);
        s2 += __shfl_xor(s2, mk, 64);
    }
    __shared__ float r1[2], r2[2];
    __shared__ float yl[128];
    if ((d & 63) == 0) { r1[d >> 6] = s1; r2[d >> 6] = s2; }
    __syncthreads();
    const float S1 = r1[0] + r1[1], S2 = r2[0] + r2[1];
    const float mu = S1 * (1.f / 128.f);
    const float var = S2 * (1.f / 128.f) - mu * mu;
    const float rstd = rsqrtf(var + 1e-5f);
    const float yln = (v - mu) * rstd * ong[d] + onb[d];
    const float zz = z[((size_t)b * 4096 + l) * 128 + d];
    yl[d] = yln * (zz / (1.f + __expf(-zz)));
    __syncthreads();
    if (d < 64) {
        float acc = 0.f;
        const float* wp = opw + d * 128;
        for (int dd = 0; dd < 128; ++dd) acc = fmaf(yl[dd], wp[dd], acc);
        res[(b * 64 + d) * 4096 + l] = acc + skipp[0] * x1[(b * 64 + d) * 4096 + l];
    }
}

// ---------------------------------------------------------------------------
// Workspace layout (floats), total 20,185,088 floats = 77.0 MB:
//   x1     @ 0           (1,048,576)  live: cf-conv .. cb-conv
//   xin_s  @ 1,048,576   (2,097,152)  live: dwconv .. finalize
//   zbuf   @ 3,145,728   (2,097,152)  live: ln_inproj .. finalize
//   xin_T  @ 5,242,880   (2,097,152)  live: transpose .. scan p2
//   xdbl   @ 7,340,032   (2,359,296)  live: xdbl_k .. scan p2
//   ybuf   @ 9,699,328   (8,388,608)  live: scan p2 .. finalize (4 dirs)
//   G      @ 18,087,936  (2,097,152)  scratch, reused:
//     conv chain (G0/G1), xin_raw (full G),
//     hseg=G0 / pseg->hstart=G1 during scan,
//     res=G0 / tmp=G1 after finalize
// ---------------------------------------------------------------------------
extern "C" void kernel_launch(void* const* d_in, const int* in_sizes, int n_in,
                              void* d_out, int out_size, void* d_ws, size_t ws_size,
                              hipStream_t stream)
{
    const float* x          = (const float*)d_in[0];
    const float* conv1_w    = (const float*)d_in[1];
    const float* conv1_b    = (const float*)d_in[2];
    const float* conv2_w    = (const float*)d_in[3];
    const float* conv2_b    = (const float*)d_in[4];
    const float* cf_w       = (const float*)d_in[5];
    const float* cf_b       = (const float*)d_in[6];
    const float* ln_g       = (const float*)d_in[7];
    const float* ln_b       = (const float*)d_in[8];
    const float* in_proj_w  = (const float*)d_in[9];
    const float* dw_w       = (const float*)d_in[10];
    const float* dw_b       = (const float*)d_in[11];
    const float* x_proj_w   = (const float*)d_in[12];
    const float* dt_proj_w  = (const float*)d_in[13];
    const float* dt_proj_b  = (const float*)d_in[14];
    const float* A_logs     = (const float*)d_in[15];
    const float* Ds         = (const float*)d_in[16];
    const float* out_norm_g = (const float*)d_in[17];
    const float* out_norm_b = (const float*)d_in[18];
    const float* out_proj_w = (const float*)d_in[19];
    const float* skip_scale = (const float*)d_in[20];
    const float* cb_w       = (const float*)d_in[21];
    const float* cb_b       = (const float*)d_in[22];

    float* ws = (float*)d_ws;
    float* x1    = ws;                 // 1,048,576
    float* xin_s = ws + 1048576;       // 2,097,152
    float* zbuf  = ws + 3145728;       // 2,097,152
    float* xin_T = ws + 5242880;       // 2,097,152
    float* xdbl  = ws + 7340032;       // 2,359,296
    float* ybuf  = ws + 9699328;       // 8,388,608
    float* G     = ws + 18087936;      // 2,097,152 scratch
    float* G0 = G;
    float* G1 = G + 1048576;

    conv3x3_k<<<256, 256, 0, stream>>>(x, conv1_w, conv1_b, nullptr, G0);
    inorm_lrelu_k<<<256, 256, 0, stream>>>(G0, G1);
    conv3x3_k<<<256, 256, 0, stream>>>(G1, conv2_w, conv2_b, nullptr, G0);
    conv3x3_k<<<256, 256, 0, stream>>>(G0, cf_w, cf_b, nullptr, x1);
    ln_inproj_k<<<512, 256, 0, stream>>>(x1, ln_g, ln_b, in_proj_w, G /*xin_raw*/, zbuf);
    dwconv_silu_k<<<8192, 256, 0, stream>>>(G /*xin_raw*/, dw_w, dw_b, xin_s);
    transpose_k<<<512, 256, 0, stream>>>(xin_s, xin_T);
    xdbl_k<<<2048, 256, 0, stream>>>(xin_s, xin_T, x_proj_w, xdbl);
    // segmented scan: G is free again (xin_raw dead after dwconv)
    scan_p1_k<<<4096, 256, 0, stream>>>(xdbl, xin_s, xin_T, A_logs, dt_proj_w,
                                        dt_proj_b, G0 /*hseg*/, G1 /*pseg*/);
    scan_combine_k<<<128, 256, 0, stream>>>(G0 /*hseg*/, G1 /*pseg->hstart*/);
    scan_p2_k<<<4096, 256, 0, stream>>>(xdbl, xin_s, xin_T, A_logs, dt_proj_w,
                                        dt_proj_b, G1 /*hstart*/, ybuf);
    finalize_k<<<16384, 128, 0, stream>>>(ybuf, xin_s, zbuf, x1, Ds, out_norm_g,
                                          out_norm_b, out_proj_w, skip_scale, G0 /*res*/);
    conv3x3_k<<<256, 256, 0, stream>>>(G0 /*res*/, cb_w, cb_b, x1, G1 /*tmp*/);
    inorm_lrelu_k<<<256, 256, 0, stream>>>(G1 /*tmp*/, (float*)d_out);
}